// Round 3
// baseline (511.873 us; speedup 1.0000x reference)
//
#include <hip/hip_runtime.h>
#include <hip/hip_cooperative_groups.h>

namespace cg = cooperative_groups;

// Problem constants
#define NB 32
#define NS 2048
#define ND 512
#define NFF 512
#define SCALE 0.044194173824159216f

#define NBLK 512   // total blocks (cooperative, 2 per CU)
#define CPB 16     // chunks (blocks) per batch in streaming phases
#define ROWS 128   // rows of x per chunk

__device__ __forceinline__ float dot4(float4 a, float4 b) {
    return a.x * b.x + a.y * b.y + a.z * b.z + a.w * b.w;
}

__device__ __forceinline__ float wave_reduce(float p) {
#pragma unroll
    for (int m = 1; m < 64; m <<= 1) p += __shfl_xor(p, m, 64);
    return p;
}

// One cooperative kernel, 5 phases separated by grid syncs:
//  P1: xwp[blk][d] = sum_{s in chunk} Wt[s]*x[b,s,d]         (stream x, HBM)
//  P2: kw[b,f] = xw.Wk[f,:] + bk[f]*swt  (256 blocks, 8/b); kwbq partials
//  P3: wqs[b,d] = SCALE*sum_f kw*Wq[f,d] (128 blocks, 4/b); cb2[b]
//  P4: ta = x.wqs + cb2; xtp[blk][d] = sum ta*x; stp[blk]    (stream x, L3)
//  P5: out[b,f] = xt.Wv[f,:] + bv[f]*st  (256 blocks, 8/b)
__global__ void __launch_bounds__(256, 2)
k_fused(const float* __restrict__ x,
        const float* __restrict__ Wq, const float* __restrict__ bq,
        const float* __restrict__ Wk, const float* __restrict__ bk,
        const float* __restrict__ Wv, const float* __restrict__ bv,
        const float* __restrict__ Wt, const float* __restrict__ bt,
        float* __restrict__ out, float* __restrict__ ws) {
    cg::grid_group grid = cg::this_grid();

    // workspace layout (floats)
    float* xwp  = ws;               // [512][512]
    float* xtp  = ws + 262144;      // [512][512]
    float* stp  = ws + 524288;      // [512]
    float* kw   = ws + 524800;      // [32][512]
    float* wqs  = ws + 541184;      // [32][512]
    float* kwbq = ws + 557568;      // [256]
    float* cb2  = ws + 557824;      // [32]

    const int blk  = blockIdx.x;
    const int t    = threadIdx.x;
    const int wv   = t >> 6;
    const int lane = t & 63;
    const int b_s  = blk >> 4;      // batch for streaming phases (P1/P4)
    const int chunk = blk & 15;

    __shared__ float4 red4[128];    // P1
    __shared__ float4 sh0[4][64];   // P4
    __shared__ float4 sh1[4][64];   // P4
    __shared__ float  sA[ND];       // P2 / P5 vector staging
    __shared__ float  part[2][128]; // P3
    __shared__ float  sW[4];        // per-wave scratch
    __shared__ float  sScalar;      // swt / st

    const float4* xb = (const float4*)(x + (size_t)b_s * NS * ND);

    // ---------------- P1: xw partials -----------------------------------
    {
        const int col = t & 127;
        const int half = t >> 7;
        const int s0 = chunk * ROWS;
        float4 acc = make_float4(0.f, 0.f, 0.f, 0.f);
#pragma unroll 4
        for (int i = 0; i < 64; i++) {
            int s = s0 + half + 2 * i;
            float w = Wt[s];
            float4 v = xb[(size_t)s * 128 + col];
            acc.x += w * v.x; acc.y += w * v.y; acc.z += w * v.z; acc.w += w * v.w;
        }
        if (half == 1) red4[col] = acc;
        __syncthreads();
        if (half == 0) {
            float4 o = red4[col];
            o.x += acc.x; o.y += acc.y; o.z += acc.z; o.w += acc.w;
            ((float4*)xwp)[(size_t)blk * 128 + col] = o;
        }
    }
    grid.sync();

    // ---------------- P2: kw + kwbq partials (blocks 0..255) ------------
    if (blk < 256) {
        const int b = blk >> 3;
        const int f0 = (blk & 7) * 64;
        float a0 = 0.f, a1 = 0.f;
        const float* p = xwp + (size_t)b * CPB * ND;
#pragma unroll
        for (int c = 0; c < CPB; c++) {
            a0 += p[c * ND + t];
            a1 += p[c * ND + 256 + t];
        }
        sA[t] = a0;
        sA[256 + t] = a1;
        if (wv == 0) {
            float a = 0.f;
#pragma unroll
            for (int j = 0; j < 32; j++) a += Wt[j * 64 + lane];
            a = wave_reduce(a);
            if (lane == 0) sScalar = a;   // swt
        }
        __syncthreads();
        const float4* xw4 = (const float4*)sA;
        const float4 xa = xw4[lane];
        const float4 xc = xw4[64 + lane];
        const float sw = sScalar;
        float cbp = 0.f;
#pragma unroll 4
        for (int j = 0; j < 16; j++) {
            int f = f0 + wv * 16 + j;
            const float4* wr = (const float4*)(Wk + (size_t)f * ND);
            float pd = dot4(xa, wr[lane]) + dot4(xc, wr[64 + lane]);
            pd = wave_reduce(pd);
            if (lane == 0) {
                float kf = pd + bk[f] * sw;
                kw[b * NFF + f] = kf;
                cbp += kf * bq[f];
            }
        }
        if (lane == 0) sW[wv] = cbp;
        __syncthreads();
        if (t == 0) kwbq[blk] = sW[0] + sW[1] + sW[2] + sW[3];
    }
    grid.sync();

    // ---------------- P3: wqs + cb2 (blocks 0..127) ---------------------
    if (blk < 128) {
        const int b = blk >> 2;
        const int d0 = (blk & 3) * 128;
        const int dl = t & 127;
        const int h = t >> 7;
        float acc = 0.f;
        const float* kwb = kw + b * NFF + h * 256;
        const float* wq = Wq + (size_t)h * 256 * ND + d0 + dl;
#pragma unroll 8
        for (int j = 0; j < 256; j++) acc += kwb[j] * wq[(size_t)j * ND];
        part[h][dl] = acc;
        __syncthreads();
        if (h == 0) wqs[b * ND + d0 + dl] = SCALE * (part[0][dl] + part[1][dl]);
        if ((blk & 3) == 0 && t == 0) {
            float s = 0.f;
#pragma unroll
            for (int k = 0; k < 8; k++) s += kwbq[b * 8 + k];
            cb2[b] = SCALE * s + bt[0];
        }
    }
    grid.sync();

    // ---------------- P4: ta + xt partials (stream x, L3-warm) ----------
    {
        const float4* wq4 = (const float4*)(wqs + b_s * ND);
        const float4 w0 = wq4[lane];
        const float4 w1 = wq4[64 + lane];
        const float c = cb2[b_s];
        float4 a0 = make_float4(0.f, 0.f, 0.f, 0.f);
        float4 a1 = make_float4(0.f, 0.f, 0.f, 0.f);
        float sta = 0.f;
#pragma unroll 2
        for (int i = 0; i < 32; i++) {
            int s = chunk * ROWS + wv * 32 + i;
            float4 v0 = xb[(size_t)s * 128 + lane];
            float4 v1 = xb[(size_t)s * 128 + 64 + lane];
            float pd = dot4(v0, w0) + dot4(v1, w1);
            pd = wave_reduce(pd);
            float ta = pd + c;
            a0.x += ta * v0.x; a0.y += ta * v0.y; a0.z += ta * v0.z; a0.w += ta * v0.w;
            a1.x += ta * v1.x; a1.y += ta * v1.y; a1.z += ta * v1.z; a1.w += ta * v1.w;
            sta += ta;
        }
        __syncthreads();   // protect sW reuse
        sh0[wv][lane] = a0;
        sh1[wv][lane] = a1;
        if (lane == 0) sW[wv] = sta;
        __syncthreads();
        float4* dst = (float4*)xtp + (size_t)blk * 128;
        if (t < 64) {
            float4 s0 = sh0[0][t], s1 = sh0[1][t], s2 = sh0[2][t], s3 = sh0[3][t];
            dst[t] = make_float4(s0.x + s1.x + s2.x + s3.x,
                                 s0.y + s1.y + s2.y + s3.y,
                                 s0.z + s1.z + s2.z + s3.z,
                                 s0.w + s1.w + s2.w + s3.w);
        } else if (t < 128) {
            int l = t - 64;
            float4 s0 = sh1[0][l], s1 = sh1[1][l], s2 = sh1[2][l], s3 = sh1[3][l];
            dst[64 + l] = make_float4(s0.x + s1.x + s2.x + s3.x,
                                      s0.y + s1.y + s2.y + s3.y,
                                      s0.z + s1.z + s2.z + s3.z,
                                      s0.w + s1.w + s2.w + s3.w);
        } else if (t == 128) {
            stp[blk] = sW[0] + sW[1] + sW[2] + sW[3];
        }
    }
    grid.sync();

    // ---------------- P5: latent output (blocks 0..255) -----------------
    if (blk < 256) {
        const int b = blk >> 3;
        const int f0 = (blk & 7) * 64;
        float a0 = 0.f, a1 = 0.f;
        const float* p = xtp + (size_t)b * CPB * ND;
#pragma unroll
        for (int c = 0; c < CPB; c++) {
            a0 += p[c * ND + t];
            a1 += p[c * ND + 256 + t];
        }
        __syncthreads();   // protect sA reuse
        sA[t] = a0;
        sA[256 + t] = a1;
        if (t == 0) {
            float s = 0.f;
#pragma unroll
            for (int c = 0; c < CPB; c++) s += stp[b * CPB + c];
            sScalar = s;   // st
        }
        __syncthreads();
        const float4* xt4 = (const float4*)sA;
        const float4 xa = xt4[lane];
        const float4 xc = xt4[64 + lane];
        const float stb = sScalar;
#pragma unroll 4
        for (int j = 0; j < 16; j++) {
            int f = f0 + wv * 16 + j;
            const float4* wr = (const float4*)(Wv + (size_t)f * ND);
            float pd = dot4(xa, wr[lane]) + dot4(xc, wr[64 + lane]);
            pd = wave_reduce(pd);
            if (lane == 0) out[b * NFF + f] = pd + bv[f] * stb;
        }
    }
}

extern "C" void kernel_launch(void* const* d_in, const int* in_sizes, int n_in,
                              void* d_out, int out_size, void* d_ws, size_t ws_size,
                              hipStream_t stream) {
    const float* x  = (const float*)d_in[0];
    const float* Wq = (const float*)d_in[1];
    const float* bq = (const float*)d_in[2];
    const float* Wk = (const float*)d_in[3];
    const float* bk = (const float*)d_in[4];
    const float* Wv = (const float*)d_in[5];
    const float* bv = (const float*)d_in[6];
    const float* Wt = (const float*)d_in[7];
    const float* bt = (const float*)d_in[8];
    float* out = (float*)d_out;
    float* wsf = (float*)d_ws;

    void* args[] = {(void*)&x, (void*)&Wq, (void*)&bq, (void*)&Wk, (void*)&bk,
                    (void*)&Wv, (void*)&bv, (void*)&Wt, (void*)&bt,
                    (void*)&out, (void*)&wsf};
    hipLaunchCooperativeKernel((void*)k_fused, dim3(NBLK), dim3(256), args, 0, stream);
}

// Round 4
// 280.716 us; speedup vs baseline: 1.8235x; 1.8235x over previous
//
#include <hip/hip_runtime.h>

// Problem constants
#define NB 32
#define NS 2048
#define ND 512
#define NFF 512
#define SCALE 0.044194173824159216f

// Streaming decomposition: 64 chunks per batch, 32 rows per chunk
#define CPB 64
#define ROWS 32

__device__ __forceinline__ float dot4(float4 a, float4 b) {
    return a.x * b.x + a.y * b.y + a.z * b.z + a.w * b.w;
}

__device__ __forceinline__ float wave_reduce(float p) {
#pragma unroll
    for (int m = 1; m < 64; m <<= 1) p += __shfl_xor(p, m, 64);
    return p;
}

// ---- K1: xwp[blk][d] = sum_{s in chunk} Wt[s]*x[b,s,d]  (pass 1, HBM) ------
// grid = NB*64 = 2048 blocks, 256 threads (8 blocks/CU -> 32 waves/CU)
__global__ void __launch_bounds__(256) k_xw(const float* __restrict__ x,
                                            const float* __restrict__ Wt,
                                            float* __restrict__ xwp) {
    const int b = blockIdx.x >> 6;
    const int chunk = blockIdx.x & 63;
    const int s0 = chunk * ROWS;
    const int t = threadIdx.x;
    const int col = t & 127;   // float4 column
    const int half = t >> 7;   // row interleave (0/1)
    const float4* xb = (const float4*)(x + (size_t)b * NS * ND);
    float4 acc = make_float4(0.f, 0.f, 0.f, 0.f);
#pragma unroll 4
    for (int i = 0; i < 16; i++) {
        int s = s0 + half + 2 * i;
        float w = Wt[s];
        float4 v = xb[(size_t)s * 128 + col];
        acc.x += w * v.x; acc.y += w * v.y; acc.z += w * v.z; acc.w += w * v.w;
    }
    __shared__ float4 red[128];
    if (half == 1) red[col] = acc;
    __syncthreads();
    if (half == 0) {
        float4 o = red[col];
        o.x += acc.x; o.y += acc.y; o.z += acc.z; o.w += acc.w;
        ((float4*)xwp)[(size_t)blockIdx.x * 128 + col] = o;
    }
}

// ---- K2: kw[b,f] = xw.Wk[f,:] + bk[f]*swt; kwbq[blk] partials --------------
// grid = 256 blocks (8 per b, 64 f each), 256 threads
__global__ void __launch_bounds__(256) k_kw(const float* __restrict__ xwp,
                                            const float* __restrict__ Wt,
                                            const float* __restrict__ Wk,
                                            const float* __restrict__ bk,
                                            const float* __restrict__ bq,
                                            float* __restrict__ kw,
                                            float* __restrict__ kwbq) {
    const int b = blockIdx.x >> 3;
    const int f0 = (blockIdx.x & 7) * 64;
    const int t = threadIdx.x;
    const int wv = t >> 6;
    const int lane = t & 63;
    __shared__ float sA[ND];
    __shared__ float sW[4];
    __shared__ float swt_s;
    // Stage A: reduce the 64 xwp partial rows of batch b
    {
        float a0 = 0.f, a1 = 0.f;
        const float* p = xwp + (size_t)b * CPB * ND + t;
#pragma unroll 8
        for (int c = 0; c < CPB; c++) {
            a0 += p[(size_t)c * ND];
            a1 += p[(size_t)c * ND + 256];
        }
        sA[t] = a0;
        sA[256 + t] = a1;
    }
    if (wv == 0) {
        float a = 0.f;
#pragma unroll
        for (int j = 0; j < 32; j++) a += Wt[j * 64 + lane];
        a = wave_reduce(a);
        if (lane == 0) swt_s = a;
    }
    __syncthreads();
    // Stage B: 16 f's per wave
    const float4* xw4 = (const float4*)sA;
    const float4 xa = xw4[lane];
    const float4 xc = xw4[64 + lane];
    const float sw = swt_s;
    float cbp = 0.f;
#pragma unroll 4
    for (int j = 0; j < 16; j++) {
        int f = f0 + wv * 16 + j;
        const float4* wr = (const float4*)(Wk + (size_t)f * ND);
        float pd = dot4(xa, wr[lane]) + dot4(xc, wr[64 + lane]);
        pd = wave_reduce(pd);
        if (lane == 0) {
            float kf = pd + bk[f] * sw;
            kw[b * NFF + f] = kf;
            cbp += kf * bq[f];
        }
    }
    if (lane == 0) sW[wv] = cbp;
    __syncthreads();
    if (t == 0) kwbq[blockIdx.x] = sW[0] + sW[1] + sW[2] + sW[3];
}

// ---- K3: wqs[b,d] = SCALE*sum_f kw[b,f]*Wq[f,d]; cb2[b] --------------------
// grid = 128 blocks (4 per b, 128 d each), 256 threads
__global__ void __launch_bounds__(256) k_wqs(const float* __restrict__ kw,
                                             const float* __restrict__ Wq,
                                             const float* __restrict__ kwbq,
                                             const float* __restrict__ bt,
                                             float* __restrict__ wqs,
                                             float* __restrict__ cb2) {
    const int b = blockIdx.x >> 2;
    const int d0 = (blockIdx.x & 3) * 128;
    const int t = threadIdx.x;
    const int dl = t & 127;
    const int h = t >> 7;
    __shared__ float part[2][128];
    float acc = 0.f;
    const float* kwb = kw + b * NFF + h * 256;
    const float* wq = Wq + (size_t)h * 256 * ND + d0 + dl;
#pragma unroll 8
    for (int j = 0; j < 256; j++) acc += kwb[j] * wq[(size_t)j * ND];
    part[h][dl] = acc;
    __syncthreads();
    if (h == 0) wqs[b * ND + d0 + dl] = SCALE * (part[0][dl] + part[1][dl]);
    if ((blockIdx.x & 3) == 0 && t == 0) {
        float s = 0.f;
#pragma unroll
        for (int k = 0; k < 8; k++) s += kwbq[b * 8 + k];
        cb2[b] = SCALE * s + bt[0];
    }
}

// ---- K4: ta = x.wqs + cb2; xtp[blk][d] = sum_s ta*x; stp[blk] (pass 2, L3) -
// grid = 2048 blocks (32 rows), 256 threads = 4 waves, 8 rows/wave
__global__ void __launch_bounds__(256) k_ta_xt(const float* __restrict__ x,
                                               const float* __restrict__ wqs,
                                               const float* __restrict__ cb2,
                                               float* __restrict__ xtp,
                                               float* __restrict__ stp) {
    const int b = blockIdx.x >> 6;
    const int chunk = blockIdx.x & 63;
    const int wv = threadIdx.x >> 6;
    const int lane = threadIdx.x & 63;
    const float4* xb = (const float4*)(x + (size_t)b * NS * ND);
    const float4* wq4 = (const float4*)(wqs + b * ND);
    const float4 w0 = wq4[lane];
    const float4 w1 = wq4[64 + lane];
    const float c = cb2[b];
    float4 a0 = make_float4(0.f, 0.f, 0.f, 0.f);
    float4 a1 = make_float4(0.f, 0.f, 0.f, 0.f);
    float sta = 0.f;
#pragma unroll 2
    for (int i = 0; i < 8; i++) {
        int s = chunk * ROWS + wv * 8 + i;
        float4 v0 = xb[(size_t)s * 128 + lane];
        float4 v1 = xb[(size_t)s * 128 + 64 + lane];
        float pd = dot4(v0, w0) + dot4(v1, w1);
        pd = wave_reduce(pd);
        float ta = pd + c;
        a0.x += ta * v0.x; a0.y += ta * v0.y; a0.z += ta * v0.z; a0.w += ta * v0.w;
        a1.x += ta * v1.x; a1.y += ta * v1.y; a1.z += ta * v1.z; a1.w += ta * v1.w;
        sta += ta;
    }
    __shared__ float4 sh0[4][64];
    __shared__ float4 sh1[4][64];
    __shared__ float sW[4];
    sh0[wv][lane] = a0;
    sh1[wv][lane] = a1;
    if (lane == 0) sW[wv] = sta;
    __syncthreads();
    const int t = threadIdx.x;
    float4* dst = (float4*)xtp + (size_t)blockIdx.x * 128;
    if (t < 64) {
        float4 s0 = sh0[0][t], s1 = sh0[1][t], s2 = sh0[2][t], s3 = sh0[3][t];
        dst[t] = make_float4(s0.x + s1.x + s2.x + s3.x,
                             s0.y + s1.y + s2.y + s3.y,
                             s0.z + s1.z + s2.z + s3.z,
                             s0.w + s1.w + s2.w + s3.w);
    } else if (t < 128) {
        int l = t - 64;
        float4 s0 = sh1[0][l], s1 = sh1[1][l], s2 = sh1[2][l], s3 = sh1[3][l];
        dst[64 + l] = make_float4(s0.x + s1.x + s2.x + s3.x,
                                  s0.y + s1.y + s2.y + s3.y,
                                  s0.z + s1.z + s2.z + s3.z,
                                  s0.w + s1.w + s2.w + s3.w);
    } else if (t == 128) {
        stp[blockIdx.x] = sW[0] + sW[1] + sW[2] + sW[3];
    }
}

// ---- K5: out[b,f] = xt.Wv[f,:] + bv[f]*st, reducing xtp/stp ----------------
// grid = 256 blocks (8 per b, 64 f each), 256 threads
__global__ void __launch_bounds__(256) k_latent(const float* __restrict__ xtp,
                                                const float* __restrict__ stp,
                                                const float* __restrict__ Wv,
                                                const float* __restrict__ bv,
                                                float* __restrict__ out) {
    const int b = blockIdx.x >> 3;
    const int f0 = (blockIdx.x & 7) * 64;
    const int t = threadIdx.x;
    const int wv = t >> 6;
    const int lane = t & 63;
    __shared__ float sA[ND];
    __shared__ float sts;
    {
        float a0 = 0.f, a1 = 0.f;
        const float* p = xtp + (size_t)b * CPB * ND + t;
#pragma unroll 8
        for (int c = 0; c < CPB; c++) {
            a0 += p[(size_t)c * ND];
            a1 += p[(size_t)c * ND + 256];
        }
        sA[t] = a0;
        sA[256 + t] = a1;
        if (t == 0) {
            float s = 0.f;
            const float* sp = stp + b * CPB;
#pragma unroll
            for (int c = 0; c < CPB; c++) s += sp[c];
            sts = s;
        }
    }
    __syncthreads();
    const float4* xt4 = (const float4*)sA;
    const float4 xa = xt4[lane];
    const float4 xc = xt4[64 + lane];
    const float stb = sts;
#pragma unroll 4
    for (int j = 0; j < 16; j++) {
        int f = f0 + wv * 16 + j;
        const float4* wr = (const float4*)(Wv + (size_t)f * ND);
        float pd = dot4(xa, wr[lane]) + dot4(xc, wr[64 + lane]);
        pd = wave_reduce(pd);
        if (lane == 0) out[b * NFF + f] = pd + bv[f] * stb;
    }
}

extern "C" void kernel_launch(void* const* d_in, const int* in_sizes, int n_in,
                              void* d_out, int out_size, void* d_ws, size_t ws_size,
                              hipStream_t stream) {
    const float* x  = (const float*)d_in[0];
    const float* Wq = (const float*)d_in[1];
    const float* bq = (const float*)d_in[2];
    const float* Wk = (const float*)d_in[3];
    const float* bk = (const float*)d_in[4];
    const float* Wv = (const float*)d_in[5];
    const float* bv = (const float*)d_in[6];
    const float* Wt = (const float*)d_in[7];
    const float* bt = (const float*)d_in[8];
    float* out = (float*)d_out;

    float* w = (float*)d_ws;
    float* xwp  = w;                 // 2048*512 = 1048576
    float* xtp  = w + 1048576;       // 1048576
    float* stp  = w + 2097152;       // 2048
    float* kw   = w + 2099200;       // 16384
    float* kwbq = w + 2115584;       // 256
    float* wqs  = w + 2115840;       // 16384
    float* cb2  = w + 2132224;       // 32

    k_xw<<<NB * CPB, 256, 0, stream>>>(x, Wt, xwp);
    k_kw<<<256, 256, 0, stream>>>(xwp, Wt, Wk, bk, bq, kw, kwbq);
    k_wqs<<<128, 256, 0, stream>>>(kw, Wq, kwbq, bt, wqs, cb2);
    k_ta_xt<<<NB * CPB, 256, 0, stream>>>(x, wqs, cb2, xtp, stp);
    k_latent<<<256, 256, 0, stream>>>(xtp, stp, Wv, bv, out);
}